// Round 1
// baseline (1225.226 us; speedup 1.0000x reference)
//
#include <hip/hip_runtime.h>

#define N_IN   128
#define N_HID  15
#define N_HIDP 16
#define N_OUT  32

// ---------------------------------------------------------------------------
// Detect int64 vs int32 edge payload: if int64, every odd 32-bit word (high
// word of a value < 2^31) is 0.
// ---------------------------------------------------------------------------
__global__ void detect_kernel(const int* __restrict__ idx, int* __restrict__ flag) {
    __shared__ int nz;
    if (threadIdx.x == 0) nz = 0;
    __syncthreads();
    if (idx[2 * threadIdx.x + 1] != 0) atomicOr(&nz, 1);
    __syncthreads();
    if (threadIdx.x == 0) *flag = (nz == 0) ? 1 : 0;
}

// In-degree (excluding self-loops), reading dst straight from edge_index.
__global__ void deg_kernel(const void* __restrict__ idx, int E,
                           const int* __restrict__ flag,
                           unsigned* __restrict__ deg) {
    int e = blockIdx.x * 256 + threadIdx.x;
    if (e >= E) return;
    int d = (*flag) ? (int)((const long long*)idx)[E + e]
                    : ((const int*)idx)[E + e];
    atomicAdd(&deg[d], 1u);
}

// ---------------------------------------------------------------------------
// Exclusive prefix scan of deg -> cursor (CSR row starts). 3 kernels:
// scan1: per-block (256 thr x 4 items = 1024) scan, block totals -> bsum.
// scan2: single-block exclusive scan of bsum (nb <= 256 required; 196 here).
// scan3: add block offset; also compute dinv = rsqrt(deg+1) (fused).
// ---------------------------------------------------------------------------
__global__ void scan1_kernel(const unsigned* __restrict__ deg,
                             unsigned* __restrict__ cursor,
                             unsigned* __restrict__ bsum, int N) {
    __shared__ unsigned sh[256];
    int t = threadIdx.x;
    int base = blockIdx.x * 1024 + t * 4;
    unsigned d[4];
#pragma unroll
    for (int j = 0; j < 4; ++j) d[j] = (base + j < N) ? deg[base + j] : 0u;
    unsigned tot = d[0] + d[1] + d[2] + d[3];
    sh[t] = tot;
    __syncthreads();
    for (int off = 1; off < 256; off <<= 1) {
        unsigned v = (t >= off) ? sh[t - off] : 0u;
        __syncthreads();
        sh[t] += v;
        __syncthreads();
    }
    unsigned ex = sh[t] - tot;   // exclusive prefix of this thread's chunk
    if (t == 255) bsum[blockIdx.x] = sh[255];
#pragma unroll
    for (int j = 0; j < 4; ++j) {
        if (base + j < N) cursor[base + j] = ex;
        ex += d[j];
    }
}

__global__ void scan2_kernel(unsigned* __restrict__ bsum, int nb) {
    __shared__ unsigned sh[256];
    int t = threadIdx.x;
    unsigned v0 = (t < nb) ? bsum[t] : 0u;
    sh[t] = v0;
    __syncthreads();
    for (int off = 1; off < 256; off <<= 1) {
        unsigned v = (t >= off) ? sh[t - off] : 0u;
        __syncthreads();
        sh[t] += v;
        __syncthreads();
    }
    if (t < nb) bsum[t] = sh[t] - v0;  // exclusive
}

__global__ void scan3_dinv_kernel(unsigned* __restrict__ cursor,
                                  const unsigned* __restrict__ bsum,
                                  const unsigned* __restrict__ deg,
                                  float* __restrict__ dinv, int N) {
    int i = blockIdx.x * 256 + threadIdx.x;
    if (i >= N) return;
    cursor[i] += bsum[i >> 10];
    dinv[i] = rsqrtf((float)deg[i] + 1.0f);  // +1 = self-loop
}

// ---------------------------------------------------------------------------
// CSR fill: srcs grouped by dst via atomic cursor. After this kernel,
// cursor[i] == row_start(i) + deg[i] (row END); agg uses base = cend - deg.
// ---------------------------------------------------------------------------
__global__ void fill_kernel(const void* __restrict__ idx, int E,
                            const int* __restrict__ flag,
                            unsigned* __restrict__ cursor,
                            int* __restrict__ srcs) {
    int e = blockIdx.x * 256 + threadIdx.x;
    if (e >= E) return;
    int s, d;
    if (*flag) {
        s = (int)((const long long*)idx)[e];
        d = (int)((const long long*)idx)[E + e];
    } else {
        s = ((const int*)idx)[e];
        d = ((const int*)idx)[E + e];
    }
    unsigned pos = atomicAdd(&cursor[d], 1u);
    srcs[pos] = s;
}

// ---------------------------------------------------------------------------
// GEMM1: hs[i][c] = (x[i] @ W1[:,c]) * dinv[i], padded to 16 ch (ch15 = 0).
// ---------------------------------------------------------------------------
__global__ __launch_bounds__(256) void gemm1_kernel(
    const float* __restrict__ x, const float* __restrict__ W1,
    const float* __restrict__ dinv, float* __restrict__ hs, int N) {
    __shared__ float Wl[N_IN * N_HIDP];
    for (int i = threadIdx.x; i < N_IN * N_HIDP; i += 256) {
        int k = i >> 4, c = i & 15;
        Wl[i] = (c < N_HID) ? W1[k * N_HID + c] : 0.f;
    }
    __syncthreads();
    const float4* __restrict__ Wl4 = (const float4*)Wl;
    const float4* __restrict__ x4  = (const float4*)x;

    int r0 = blockIdx.x * 512 + threadIdx.x;
    int r1 = r0 + 256;
    int r0c = r0 < N ? r0 : N - 1;
    int r1c = r1 < N ? r1 : N - 1;

    float acc0[16], acc1[16];
#pragma unroll
    for (int c = 0; c < 16; ++c) { acc0[c] = 0.f; acc1[c] = 0.f; }

    for (int k4 = 0; k4 < 32; ++k4) {
        float4 xv0 = x4[r0c * 32 + k4];
        float4 xv1 = x4[r1c * 32 + k4];
        float xs0[4] = {xv0.x, xv0.y, xv0.z, xv0.w};
        float xs1[4] = {xv1.x, xv1.y, xv1.z, xv1.w};
#pragma unroll
        for (int t = 0; t < 4; ++t) {
            int k = k4 * 4 + t;
            float4 wa = Wl4[k * 4 + 0];
            float4 wb = Wl4[k * 4 + 1];
            float4 wc = Wl4[k * 4 + 2];
            float4 wd = Wl4[k * 4 + 3];
            float wf[16] = {wa.x, wa.y, wa.z, wa.w, wb.x, wb.y, wb.z, wb.w,
                            wc.x, wc.y, wc.z, wc.w, wd.x, wd.y, wd.z, wd.w};
#pragma unroll
            for (int c = 0; c < 16; ++c) {
                acc0[c] = fmaf(xs0[t], wf[c], acc0[c]);
                acc1[c] = fmaf(xs1[t], wf[c], acc1[c]);
            }
        }
    }
    float4* __restrict__ hs4 = (float4*)hs;
    if (r0 < N) {
        float di = dinv[r0];
#pragma unroll
        for (int j = 0; j < 4; ++j)
            hs4[r0 * 4 + j] = make_float4(acc0[4*j]*di, acc0[4*j+1]*di,
                                          acc0[4*j+2]*di, acc0[4*j+3]*di);
    }
    if (r1 < N) {
        float di = dinv[r1];
#pragma unroll
        for (int j = 0; j < 4; ++j)
            hs4[r1 * 4 + j] = make_float4(acc1[4*j]*di, acc1[4*j+1]*di,
                                          acc1[4*j+2]*di, acc1[4*j+3]*di);
    }
}

// ---------------------------------------------------------------------------
// agg1: one 64-lane wave per dst node. Lanes = 4 edge-groups x 16 channels.
// Each group streams its strided slice of the node's CSR row (2 gathers in
// flight via x2 unroll), then shfl_xor reduce over the 4 groups. Epilogue
// fuses self-loop + bias + ReLU + dinv pre-scale for layer 2:
//   hs2[i] = relu(dinv*(sum + hs[i]) + b1) * dinv        (pad ch -> 0)
// No atomics: one coalesced 64 B store per node.
// ---------------------------------------------------------------------------
__global__ __launch_bounds__(256) void agg1_kernel(
    const int* __restrict__ srcs, const unsigned* __restrict__ cend,
    const unsigned* __restrict__ deg, const float* __restrict__ hs,
    const float* __restrict__ dinv, const float* __restrict__ b1,
    float* __restrict__ hs2, int N) {
    int node = blockIdx.x * 4 + (threadIdx.x >> 6);
    if (node >= N) return;
    int lane = threadIdx.x & 63;
    int k = lane >> 4, c = lane & 15;
    unsigned dg = deg[node];
    unsigned base = cend[node] - dg;
    float acc = 0.f;
    unsigned t = k;
    for (; t + 4 < dg; t += 8) {
        int s0 = srcs[base + t];
        int s1 = srcs[base + t + 4];
        float v0 = hs[(size_t)s0 * N_HIDP + c];
        float v1 = hs[(size_t)s1 * N_HIDP + c];
        acc += v0 + v1;
    }
    if (t < dg) acc += hs[(size_t)srcs[base + t] * N_HIDP + c];
    acc += __shfl_xor(acc, 16);
    acc += __shfl_xor(acc, 32);
    if (k == 0) {
        float di = dinv[node];
        float self = hs[(size_t)node * N_HIDP + c];
        float b = (c < N_HID) ? b1[c] : 0.f;
        float v = fmaxf(di * (acc + self) + b, 0.f);
        hs2[(size_t)node * N_HIDP + c] = v * di;
    }
}

// ---------------------------------------------------------------------------
// agg2: same gather-reduce, epilogue fuses the 15x32 W2 GEMM:
//   u[c] = dinv*(sum + hs2[i][c]);  out[i][j] = sum_k u[k]*W2[k][j] + b2[j]
// u is broadcast across the wave via __shfl; W2 staged in LDS.
// ---------------------------------------------------------------------------
__global__ __launch_bounds__(256) void agg2_kernel(
    const int* __restrict__ srcs, const unsigned* __restrict__ cend,
    const unsigned* __restrict__ deg, const float* __restrict__ hs2,
    const float* __restrict__ dinv, const float* __restrict__ W2,
    const float* __restrict__ b2, float* __restrict__ out, int N) {
    __shared__ float W2l[N_HID * N_OUT];
    for (int t = threadIdx.x; t < N_HID * N_OUT; t += 256) W2l[t] = W2[t];
    __syncthreads();
    int node = blockIdx.x * 4 + (threadIdx.x >> 6);
    if (node >= N) return;
    int lane = threadIdx.x & 63;
    int k = lane >> 4, c = lane & 15;
    unsigned dg = deg[node];
    unsigned base = cend[node] - dg;
    float acc = 0.f;
    unsigned t = k;
    for (; t + 4 < dg; t += 8) {
        int s0 = srcs[base + t];
        int s1 = srcs[base + t + 4];
        float v0 = hs2[(size_t)s0 * N_HIDP + c];
        float v1 = hs2[(size_t)s1 * N_HIDP + c];
        acc += v0 + v1;
    }
    if (t < dg) acc += hs2[(size_t)srcs[base + t] * N_HIDP + c];
    acc += __shfl_xor(acc, 16);
    acc += __shfl_xor(acc, 32);
    float di = dinv[node];
    float u = di * (acc + hs2[(size_t)node * N_HIDP + c]);  // c==15 -> 0
    int j = lane & 31;
    float a = b2[j];
#pragma unroll
    for (int kk = 0; kk < N_HID; ++kk)
        a = fmaf(__shfl(u, kk), W2l[kk * N_OUT + j], a);
    if (lane < 32) out[(size_t)node * N_OUT + j] = a;
}

// ---------------------------------------------------------------------------
extern "C" void kernel_launch(void* const* d_in, const int* in_sizes, int n_in,
                              void* d_out, int out_size, void* d_ws, size_t ws_size,
                              hipStream_t stream) {
    const float* x   = (const float*)d_in[0];
    const void*  eix = d_in[1];
    const float* W1  = (const float*)d_in[2];
    const float* b1  = (const float*)d_in[3];
    const float* W2  = (const float*)d_in[4];
    const float* b2  = (const float*)d_in[5];
    float* out = (float*)d_out;

    const int N = in_sizes[0] / N_IN;   // 200000
    const int E = in_sizes[1] / 2;      // 6400000

    char* ws = (char*)d_ws;
    size_t off = 0;
    auto alloc = [&](size_t bytes) -> void* {
        void* p = ws + off;
        off += (bytes + 255) & ~(size_t)255;
        return p;
    };
    unsigned* deg    = (unsigned*)alloc((size_t)N * 4);
    float*    dinv   = (float*)alloc((size_t)N * 4);
    unsigned* cursor = (unsigned*)alloc((size_t)N * 4);
    unsigned* bsum   = (unsigned*)alloc(256 * 4);
    int*      srcs   = (int*)alloc((size_t)E * 4);
    float*    hs     = (float*)alloc((size_t)N * N_HIDP * 4);
    float*    hs2    = (float*)alloc((size_t)N * N_HIDP * 4);
    int*      flag   = (int*)alloc(256);

    hipMemsetAsync(deg, 0, (size_t)N * 4, stream);

    detect_kernel<<<1, 256, 0, stream>>>((const int*)eix, flag);
    deg_kernel<<<(E + 255) / 256, 256, 0, stream>>>(eix, E, flag, deg);

    const int nb = (N + 1023) / 1024;   // 196 <= 256 (scan2 single-block limit)
    scan1_kernel<<<nb, 256, 0, stream>>>(deg, cursor, bsum, N);
    scan2_kernel<<<1, 256, 0, stream>>>(bsum, nb);
    scan3_dinv_kernel<<<(N + 255) / 256, 256, 0, stream>>>(cursor, bsum, deg, dinv, N);
    fill_kernel<<<(E + 255) / 256, 256, 0, stream>>>(eix, E, flag, cursor, srcs);

    gemm1_kernel<<<(N + 511) / 512, 256, 0, stream>>>(x, W1, dinv, hs, N);
    agg1_kernel<<<(N + 3) / 4, 256, 0, stream>>>(srcs, cursor, deg, hs, dinv, b1, hs2, N);
    agg2_kernel<<<(N + 3) / 4, 256, 0, stream>>>(srcs, cursor, deg, hs2, dinv, W2, b2, out, N);
}

// Round 2
// 1055.889 us; speedup vs baseline: 1.1604x; 1.1604x over previous
//
#include <hip/hip_runtime.h>

#define N_IN   128
#define N_HID  15
#define N_HIDP 16
#define N_OUT  32
#define NREP   8

// ---------------------------------------------------------------------------
// Detect int64 vs int32 edge payload: if int64, every odd 32-bit word (high
// word of a value < 2^31) is 0.
// ---------------------------------------------------------------------------
__global__ void detect_kernel(const int* __restrict__ idx, int* __restrict__ flag) {
    __shared__ int nz;
    if (threadIdx.x == 0) nz = 0;
    __syncthreads();
    if (idx[2 * threadIdx.x + 1] != 0) atomicOr(&nz, 1);
    __syncthreads();
    if (threadIdx.x == 0) *flag = (nz == 0) ? 1 : 0;
}

// ---------------------------------------------------------------------------
// In-degree, 8-way replicated counters to cut same-address atomic contention.
// Edge->(thread,k) and ->replica mapping MUST match fill_kernel exactly so the
// per-(node,replica) counts equal the number of fetch-adds fill does there.
// ---------------------------------------------------------------------------
__global__ void deg_kernel(const void* __restrict__ idx, int E,
                           const int* __restrict__ flag,
                           unsigned* __restrict__ deg_r, int N) {
    const int tid = threadIdx.x;
    const long long base = (long long)blockIdx.x * 1024 + tid;
    const int r = ((blockIdx.x << 2) + (tid >> 6)) & (NREP - 1);
    unsigned* __restrict__ dr = deg_r + (size_t)r * N;
    const bool is64 = (*flag != 0);
    const long long* p64 = (const long long*)idx;
    const int*       p32 = (const int*)idx;

    int d[4]; bool ok[4];
#pragma unroll
    for (int k = 0; k < 4; ++k) {
        long long e = base + (long long)k * 256;
        ok[k] = (e < E);
        long long ec = ok[k] ? e : 0;
        d[k] = is64 ? (int)p64[E + ec] : p32[E + ec];
    }
#pragma unroll
    for (int k = 0; k < 4; ++k)
        if (ok[k]) atomicAdd(&dr[d[k]], 1u);
}

// ---------------------------------------------------------------------------
// scan1: per-block (256 thr x 4 nodes) scan. Sums the 8 replicas on the fly
// and writes the combined deg[] for later use (dinv + agg row lengths).
// ---------------------------------------------------------------------------
__global__ void scan1_kernel(const unsigned* __restrict__ deg_r,
                             unsigned* __restrict__ deg,
                             unsigned* __restrict__ cursor,
                             unsigned* __restrict__ bsum, int N) {
    __shared__ unsigned sh[256];
    int t = threadIdx.x;
    int base = blockIdx.x * 1024 + t * 4;
    unsigned d[4] = {0u, 0u, 0u, 0u};
    for (int r = 0; r < NREP; ++r) {
        const unsigned* __restrict__ dr = deg_r + (size_t)r * N;
#pragma unroll
        for (int j = 0; j < 4; ++j)
            if (base + j < N) d[j] += dr[base + j];
    }
#pragma unroll
    for (int j = 0; j < 4; ++j)
        if (base + j < N) deg[base + j] = d[j];
    unsigned tot = d[0] + d[1] + d[2] + d[3];
    sh[t] = tot;
    __syncthreads();
    for (int off = 1; off < 256; off <<= 1) {
        unsigned v = (t >= off) ? sh[t - off] : 0u;
        __syncthreads();
        sh[t] += v;
        __syncthreads();
    }
    unsigned ex = sh[t] - tot;   // exclusive prefix of this thread's chunk
    if (t == 255) bsum[blockIdx.x] = sh[255];
#pragma unroll
    for (int j = 0; j < 4; ++j) {
        if (base + j < N) cursor[base + j] = ex;
        ex += d[j];
    }
}

__global__ void scan2_kernel(unsigned* __restrict__ bsum, int nb) {
    __shared__ unsigned sh[256];
    int t = threadIdx.x;
    unsigned v0 = (t < nb) ? bsum[t] : 0u;
    sh[t] = v0;
    __syncthreads();
    for (int off = 1; off < 256; off <<= 1) {
        unsigned v = (t >= off) ? sh[t - off] : 0u;
        __syncthreads();
        sh[t] += v;
        __syncthreads();
    }
    if (t < nb) bsum[t] = sh[t] - v0;  // exclusive
}

// ---------------------------------------------------------------------------
// scan3: cursor[i] -> absolute row_start (stays un-mutated; agg uses it as
// the row base). Per-replica sub-cursors get disjoint sub-ranges of the row:
//   cur_r[r][i] = row_start[i] + sum_{r'<r} deg_r[r'][i]
// Also computes dinv = rsqrt(deg+1) (+1 = self-loop).
// ---------------------------------------------------------------------------
__global__ void scan3_kernel(unsigned* __restrict__ cursor,
                             const unsigned* __restrict__ bsum,
                             const unsigned* __restrict__ deg_r,
                             const unsigned* __restrict__ deg,
                             unsigned* __restrict__ cur_r,
                             float* __restrict__ dinv, int N) {
    int i = blockIdx.x * 256 + threadIdx.x;
    if (i >= N) return;
    unsigned rs = cursor[i] + bsum[i >> 10];
    cursor[i] = rs;
    unsigned run = rs;
#pragma unroll
    for (int r = 0; r < NREP; ++r) {
        cur_r[(size_t)r * N + i] = run;
        run += deg_r[(size_t)r * N + i];
    }
    dinv[i] = rsqrtf((float)deg[i] + 1.0f);
}

// ---------------------------------------------------------------------------
// CSR fill: 4 edges/thread, phase-split (loads -> 4 independent fetch-adds ->
// stores) for ILP; replicated cursors cut same-address contention 8x.
// ---------------------------------------------------------------------------
__global__ void fill_kernel(const void* __restrict__ idx, int E,
                            const int* __restrict__ flag,
                            unsigned* __restrict__ cur_r,
                            int* __restrict__ srcs, int N) {
    const int tid = threadIdx.x;
    const long long base = (long long)blockIdx.x * 1024 + tid;
    const int r = ((blockIdx.x << 2) + (tid >> 6)) & (NREP - 1);
    unsigned* __restrict__ cr = cur_r + (size_t)r * N;
    const bool is64 = (*flag != 0);
    const long long* p64 = (const long long*)idx;
    const int*       p32 = (const int*)idx;

    int s[4], d[4]; bool ok[4];
#pragma unroll
    for (int k = 0; k < 4; ++k) {
        long long e = base + (long long)k * 256;
        ok[k] = (e < E);
        long long ec = ok[k] ? e : 0;
        if (is64) { s[k] = (int)p64[ec]; d[k] = (int)p64[E + ec]; }
        else      { s[k] = p32[ec];      d[k] = p32[E + ec]; }
    }
    unsigned pos[4];
#pragma unroll
    for (int k = 0; k < 4; ++k)
        if (ok[k]) pos[k] = atomicAdd(&cr[d[k]], 1u);
#pragma unroll
    for (int k = 0; k < 4; ++k)
        if (ok[k]) srcs[pos[k]] = s[k];
}

// ---------------------------------------------------------------------------
// GEMM1: hs[i][c] = (x[i] @ W1[:,c]) * dinv[i], padded to 16 ch (ch15 = 0).
// ---------------------------------------------------------------------------
__global__ __launch_bounds__(256) void gemm1_kernel(
    const float* __restrict__ x, const float* __restrict__ W1,
    const float* __restrict__ dinv, float* __restrict__ hs, int N) {
    __shared__ float Wl[N_IN * N_HIDP];
    for (int i = threadIdx.x; i < N_IN * N_HIDP; i += 256) {
        int k = i >> 4, c = i & 15;
        Wl[i] = (c < N_HID) ? W1[k * N_HID + c] : 0.f;
    }
    __syncthreads();
    const float4* __restrict__ Wl4 = (const float4*)Wl;
    const float4* __restrict__ x4  = (const float4*)x;

    int r0 = blockIdx.x * 512 + threadIdx.x;
    int r1 = r0 + 256;
    int r0c = r0 < N ? r0 : N - 1;
    int r1c = r1 < N ? r1 : N - 1;

    float acc0[16], acc1[16];
#pragma unroll
    for (int c = 0; c < 16; ++c) { acc0[c] = 0.f; acc1[c] = 0.f; }

    for (int k4 = 0; k4 < 32; ++k4) {
        float4 xv0 = x4[r0c * 32 + k4];
        float4 xv1 = x4[r1c * 32 + k4];
        float xs0[4] = {xv0.x, xv0.y, xv0.z, xv0.w};
        float xs1[4] = {xv1.x, xv1.y, xv1.z, xv1.w};
#pragma unroll
        for (int t = 0; t < 4; ++t) {
            int k = k4 * 4 + t;
            float4 wa = Wl4[k * 4 + 0];
            float4 wb = Wl4[k * 4 + 1];
            float4 wc = Wl4[k * 4 + 2];
            float4 wd = Wl4[k * 4 + 3];
            float wf[16] = {wa.x, wa.y, wa.z, wa.w, wb.x, wb.y, wb.z, wb.w,
                            wc.x, wc.y, wc.z, wc.w, wd.x, wd.y, wd.z, wd.w};
#pragma unroll
            for (int c = 0; c < 16; ++c) {
                acc0[c] = fmaf(xs0[t], wf[c], acc0[c]);
                acc1[c] = fmaf(xs1[t], wf[c], acc1[c]);
            }
        }
    }
    float4* __restrict__ hs4 = (float4*)hs;
    if (r0 < N) {
        float di = dinv[r0];
#pragma unroll
        for (int j = 0; j < 4; ++j)
            hs4[r0 * 4 + j] = make_float4(acc0[4*j]*di, acc0[4*j+1]*di,
                                          acc0[4*j+2]*di, acc0[4*j+3]*di);
    }
    if (r1 < N) {
        float di = dinv[r1];
#pragma unroll
        for (int j = 0; j < 4; ++j)
            hs4[r1 * 4 + j] = make_float4(acc1[4*j]*di, acc1[4*j+1]*di,
                                          acc1[4*j+2]*di, acc1[4*j+3]*di);
    }
}

// ---------------------------------------------------------------------------
// agg1: one 64-lane wave per dst node. Lanes = 4 edge-groups x 16 channels.
// 4 gathers in flight per lane (x4 unroll), shfl_xor reduce over groups.
// Epilogue fuses self-loop + bias + ReLU + dinv pre-scale for layer 2.
// No atomics: one coalesced 64 B store per node.
// ---------------------------------------------------------------------------
__global__ __launch_bounds__(256) void agg1_kernel(
    const int* __restrict__ srcs, const unsigned* __restrict__ rowst,
    const unsigned* __restrict__ deg, const float* __restrict__ hs,
    const float* __restrict__ dinv, const float* __restrict__ b1,
    float* __restrict__ hs2, int N) {
    int node = blockIdx.x * 4 + (threadIdx.x >> 6);
    if (node >= N) return;
    int lane = threadIdx.x & 63;
    int k = lane >> 4, c = lane & 15;
    unsigned dg = deg[node];
    unsigned base = rowst[node];
    float acc = 0.f;
    unsigned t = k;
    for (; t + 12 < dg; t += 16) {
        int s0 = srcs[base + t];
        int s1 = srcs[base + t + 4];
        int s2 = srcs[base + t + 8];
        int s3 = srcs[base + t + 12];
        float v0 = hs[(size_t)s0 * N_HIDP + c];
        float v1 = hs[(size_t)s1 * N_HIDP + c];
        float v2 = hs[(size_t)s2 * N_HIDP + c];
        float v3 = hs[(size_t)s3 * N_HIDP + c];
        acc += (v0 + v1) + (v2 + v3);
    }
    for (; t < dg; t += 4)
        acc += hs[(size_t)srcs[base + t] * N_HIDP + c];
    acc += __shfl_xor(acc, 16);
    acc += __shfl_xor(acc, 32);
    if (k == 0) {
        float di = dinv[node];
        float self = hs[(size_t)node * N_HIDP + c];
        float b = (c < N_HID) ? b1[c] : 0.f;
        float v = fmaxf(di * (acc + self) + b, 0.f);
        hs2[(size_t)node * N_HIDP + c] = v * di;
    }
}

// ---------------------------------------------------------------------------
// agg2: same gather-reduce, epilogue fuses the 15x32 W2 GEMM:
//   u[c] = dinv*(sum + hs2[i][c]);  out[i][j] = sum_k u[k]*W2[k][j] + b2[j]
// u is broadcast across the wave via __shfl; W2 staged in LDS.
// ---------------------------------------------------------------------------
__global__ __launch_bounds__(256) void agg2_kernel(
    const int* __restrict__ srcs, const unsigned* __restrict__ rowst,
    const unsigned* __restrict__ deg, const float* __restrict__ hs2,
    const float* __restrict__ dinv, const float* __restrict__ W2,
    const float* __restrict__ b2, float* __restrict__ out, int N) {
    __shared__ float W2l[N_HID * N_OUT];
    for (int t = threadIdx.x; t < N_HID * N_OUT; t += 256) W2l[t] = W2[t];
    __syncthreads();
    int node = blockIdx.x * 4 + (threadIdx.x >> 6);
    if (node >= N) return;
    int lane = threadIdx.x & 63;
    int k = lane >> 4, c = lane & 15;
    unsigned dg = deg[node];
    unsigned base = rowst[node];
    float acc = 0.f;
    unsigned t = k;
    for (; t + 12 < dg; t += 16) {
        int s0 = srcs[base + t];
        int s1 = srcs[base + t + 4];
        int s2 = srcs[base + t + 8];
        int s3 = srcs[base + t + 12];
        float v0 = hs2[(size_t)s0 * N_HIDP + c];
        float v1 = hs2[(size_t)s1 * N_HIDP + c];
        float v2 = hs2[(size_t)s2 * N_HIDP + c];
        float v3 = hs2[(size_t)s3 * N_HIDP + c];
        acc += (v0 + v1) + (v2 + v3);
    }
    for (; t < dg; t += 4)
        acc += hs2[(size_t)srcs[base + t] * N_HIDP + c];
    acc += __shfl_xor(acc, 16);
    acc += __shfl_xor(acc, 32);
    float di = dinv[node];
    float u = di * (acc + hs2[(size_t)node * N_HIDP + c]);  // c==15 -> 0
    int j = lane & 31;
    float a = b2[j];
#pragma unroll
    for (int kk = 0; kk < N_HID; ++kk)
        a = fmaf(__shfl(u, kk), W2l[kk * N_OUT + j], a);
    if (lane < 32) out[(size_t)node * N_OUT + j] = a;
}

// ---------------------------------------------------------------------------
extern "C" void kernel_launch(void* const* d_in, const int* in_sizes, int n_in,
                              void* d_out, int out_size, void* d_ws, size_t ws_size,
                              hipStream_t stream) {
    const float* x   = (const float*)d_in[0];
    const void*  eix = d_in[1];
    const float* W1  = (const float*)d_in[2];
    const float* b1  = (const float*)d_in[3];
    const float* W2  = (const float*)d_in[4];
    const float* b2  = (const float*)d_in[5];
    float* out = (float*)d_out;

    const int N = in_sizes[0] / N_IN;   // 200000
    const int E = in_sizes[1] / 2;      // 6400000

    char* ws = (char*)d_ws;
    size_t off = 0;
    auto alloc = [&](size_t bytes) -> void* {
        void* p = ws + off;
        off += (bytes + 255) & ~(size_t)255;
        return p;
    };
    unsigned* deg_r  = (unsigned*)alloc((size_t)NREP * N * 4);
    unsigned* deg    = (unsigned*)alloc((size_t)N * 4);
    float*    dinv   = (float*)alloc((size_t)N * 4);
    unsigned* cursor = (unsigned*)alloc((size_t)N * 4);
    unsigned* cur_r  = (unsigned*)alloc((size_t)NREP * N * 4);
    unsigned* bsum   = (unsigned*)alloc(256 * 4);
    int*      srcs   = (int*)alloc((size_t)E * 4);
    float*    hs     = (float*)alloc((size_t)N * N_HIDP * 4);
    float*    hs2    = (float*)alloc((size_t)N * N_HIDP * 4);
    int*      flag   = (int*)alloc(256);

    hipMemsetAsync(deg_r, 0, (size_t)NREP * N * 4, stream);

    detect_kernel<<<1, 256, 0, stream>>>((const int*)eix, flag);

    const int eb = (E + 1023) / 1024;   // 4 edges/thread
    deg_kernel<<<eb, 256, 0, stream>>>(eix, E, flag, deg_r, N);

    const int nb = (N + 1023) / 1024;   // 196 <= 256 (scan2 single-block limit)
    scan1_kernel<<<nb, 256, 0, stream>>>(deg_r, deg, cursor, bsum, N);
    scan2_kernel<<<1, 256, 0, stream>>>(bsum, nb);
    scan3_kernel<<<(N + 255) / 256, 256, 0, stream>>>(cursor, bsum, deg_r, deg,
                                                      cur_r, dinv, N);
    fill_kernel<<<eb, 256, 0, stream>>>(eix, E, flag, cur_r, srcs, N);

    gemm1_kernel<<<(N + 511) / 512, 256, 0, stream>>>(x, W1, dinv, hs, N);
    agg1_kernel<<<(N + 3) / 4, 256, 0, stream>>>(srcs, cursor, deg, hs, dinv, b1, hs2, N);
    agg2_kernel<<<(N + 3) / 4, 256, 0, stream>>>(srcs, cursor, deg, hs2, dinv, W2, b2, out, N);
}

// Round 4
// 651.441 us; speedup vs baseline: 1.8808x; 1.6209x over previous
//
#include <hip/hip_runtime.h>

#define N_IN   128
#define N_HID  15
#define N_HIDP 16
#define N_OUT  32

// Radix-partition CSR build parameters.
// Assumptions (valid for this problem: N=200000, E=6.4M):
//   N <= 262144  (scanB covers <= 512 buckets of 512 nodes)
//   N <  2^23    (src packs into 32-QSHIFT = 23 bits)
#define NBLK1  1024          // blocks in hist/place (chunking must match)
#define QSHIFT 9             // bucket = dst >> 9  (512 nodes per bucket)
#define QNODES 512
#define QMAXQ  2048          // LDS table cap in hist/place

// ---------------------------------------------------------------------------
// Detect int64 vs int32 edge payload: if int64, every odd 32-bit word (high
// word of a value < 2^31) is 0.
// ---------------------------------------------------------------------------
__global__ void detect_kernel(const int* __restrict__ idx, int* __restrict__ flag) {
    __shared__ int nz;
    if (threadIdx.x == 0) nz = 0;
    __syncthreads();
    if (idx[2 * threadIdx.x + 1] != 0) atomicOr(&nz, 1);
    __syncthreads();
    if (threadIdx.x == 0) *flag = (nz == 0) ? 1 : 0;
}

// ---------------------------------------------------------------------------
// hist: per-block LDS histogram over dst buckets. ghist[q*NBLK1 + b] = count
// of edges in block b's chunk with dst in bucket q. No global atomics.
// ---------------------------------------------------------------------------
__global__ __launch_bounds__(256) void hist_kernel(
    const void* __restrict__ idx, int E, const int* __restrict__ flag,
    unsigned* __restrict__ ghist, int NQ) {
    __shared__ unsigned h[QMAXQ];
    for (int q = threadIdx.x; q < NQ; q += 256) h[q] = 0u;
    __syncthreads();
    const bool is64 = (*flag != 0);
    const long long* p64 = (const long long*)idx;
    const int*       p32 = (const int*)idx;
    const int epb = (E + NBLK1 - 1) / NBLK1;
    const int lo = blockIdx.x * epb;
    const int hi = min(lo + epb, E);
    for (int e = lo + threadIdx.x; e < hi; e += 256) {
        int d = is64 ? (int)p64[E + e] : p32[E + e];
        atomicAdd(&h[d >> QSHIFT], 1u);
    }
    __syncthreads();
    for (int q = threadIdx.x; q < NQ; q += 256)
        ghist[(size_t)q * NBLK1 + blockIdx.x] = h[q];
}

// ---------------------------------------------------------------------------
// Generic 3-kernel exclusive scan over M = NQ*NBLK1 elements (M % 1024 == 0).
// scanA: in-place per-1024-block exclusive scan, block total -> bsum.
// (one scanA block == one bucket row, so bsum[q] = bucket edge count)
// ---------------------------------------------------------------------------
__global__ void scanA_kernel(unsigned* __restrict__ a, unsigned* __restrict__ bsum) {
    __shared__ unsigned sh[256];
    int t = threadIdx.x;
    size_t base = (size_t)blockIdx.x * 1024 + t * 4;
    unsigned d0 = a[base], d1 = a[base + 1], d2 = a[base + 2], d3 = a[base + 3];
    unsigned tot = d0 + d1 + d2 + d3;
    sh[t] = tot;
    __syncthreads();
    for (int off = 1; off < 256; off <<= 1) {
        unsigned v = (t >= off) ? sh[t - off] : 0u;
        __syncthreads();
        sh[t] += v;
        __syncthreads();
    }
    unsigned ex = sh[t] - tot;
    if (t == 255) bsum[blockIdx.x] = sh[255];
    a[base] = ex;
    a[base + 1] = ex + d0;
    a[base + 2] = ex + d0 + d1;
    a[base + 3] = ex + d0 + d1 + d2;
}

// scanB: single block, exclusive scan of nb <= 512 partials (2 per thread).
__global__ void scanB_kernel(unsigned* __restrict__ bsum, int nb) {
    __shared__ unsigned sh[256];
    int t = threadIdx.x;
    unsigned v0 = (2 * t < nb) ? bsum[2 * t] : 0u;
    unsigned v1 = (2 * t + 1 < nb) ? bsum[2 * t + 1] : 0u;
    unsigned tot = v0 + v1;
    sh[t] = tot;
    __syncthreads();
    for (int off = 1; off < 256; off <<= 1) {
        unsigned v = (t >= off) ? sh[t - off] : 0u;
        __syncthreads();
        sh[t] += v;
        __syncthreads();
    }
    unsigned ex = sh[t] - tot;
    if (2 * t < nb) bsum[2 * t] = ex;
    if (2 * t + 1 < nb) bsum[2 * t + 1] = ex + v0;
}

// scanC: add block offsets back.
__global__ void scanC_kernel(unsigned* __restrict__ a, const unsigned* __restrict__ bsum) {
    size_t base = (size_t)blockIdx.x * 1024 + threadIdx.x * 4;
    unsigned b = bsum[blockIdx.x];
    a[base] += b; a[base + 1] += b; a[base + 2] += b; a[base + 3] += b;
}

// ---------------------------------------------------------------------------
// place: re-read edges with the SAME chunking as hist; LDS cursors = scanned
// goff[q][b]; write packed record (src<<QSHIFT)|local_node into the bucket-
// contiguous segment. Per-(block,bucket) writes are sequential runs (~16
// records = 64 B) -> near-full-line writes. No global atomics.
// ---------------------------------------------------------------------------
__global__ __launch_bounds__(256) void place_kernel(
    const void* __restrict__ idx, int E, const int* __restrict__ flag,
    const unsigned* __restrict__ goff, unsigned* __restrict__ grecs, int NQ) {
    __shared__ unsigned cur[QMAXQ];
    for (int q = threadIdx.x; q < NQ; q += 256)
        cur[q] = goff[(size_t)q * NBLK1 + blockIdx.x];
    __syncthreads();
    const bool is64 = (*flag != 0);
    const long long* p64 = (const long long*)idx;
    const int*       p32 = (const int*)idx;
    const int epb = (E + NBLK1 - 1) / NBLK1;
    const int lo = blockIdx.x * epb;
    const int hi = min(lo + epb, E);
    for (int e = lo + threadIdx.x; e < hi; e += 256) {
        int s, d;
        if (is64) { s = (int)p64[e]; d = (int)p64[E + e]; }
        else      { s = p32[e];      d = p32[E + e]; }
        unsigned pos = atomicAdd(&cur[d >> QSHIFT], 1u);
        grecs[pos] = ((unsigned)s << QSHIFT) | (unsigned)(d & (QNODES - 1));
    }
}

// ---------------------------------------------------------------------------
// build: one block per bucket. Records are contiguous; LDS histogram of the
// 512 local degrees, LDS block scan -> row starts, write deg/rowst/dinv
// sequentially, then place srcs. The bucket's ~64 KB srcs region is written
// by this block only -> full-line L2 writebacks. Only LDS atomics.
// ---------------------------------------------------------------------------
__global__ __launch_bounds__(256) void build_kernel(
    const unsigned* __restrict__ grecs, const unsigned* __restrict__ goff,
    int E, int N, int NQ, unsigned* __restrict__ rowst,
    unsigned* __restrict__ deg, float* __restrict__ dinv,
    int* __restrict__ srcs) {
    __shared__ unsigned dl[QNODES];
    __shared__ unsigned rl[QNODES];
    __shared__ unsigned cnt[QNODES];
    __shared__ unsigned sc[256];
    const int q = blockIdx.x;
    const int lo = q << QSHIFT;
    const int nn = min(QNODES, N - lo);
    const unsigned rbase = goff[(size_t)q * NBLK1];
    const unsigned rend  = (q + 1 < NQ) ? goff[(size_t)(q + 1) * NBLK1] : (unsigned)E;
    const int t = threadIdx.x;
    dl[2 * t] = 0u; dl[2 * t + 1] = 0u;
    cnt[2 * t] = 0u; cnt[2 * t + 1] = 0u;
    __syncthreads();
    for (unsigned i = rbase + t; i < rend; i += 256)
        atomicAdd(&dl[grecs[i] & (QNODES - 1u)], 1u);
    __syncthreads();
    unsigned d0 = dl[2 * t], d1 = dl[2 * t + 1];
    unsigned tot = d0 + d1;
    sc[t] = tot;
    __syncthreads();
    for (int off = 1; off < 256; off <<= 1) {
        unsigned v = (t >= off) ? sc[t - off] : 0u;
        __syncthreads();
        sc[t] += v;
        __syncthreads();
    }
    unsigned ex = sc[t] - tot;
    rl[2 * t]     = rbase + ex;
    rl[2 * t + 1] = rbase + ex + d0;
    if (2 * t < nn) {
        rowst[lo + 2 * t] = rl[2 * t];
        deg[lo + 2 * t] = d0;
        dinv[lo + 2 * t] = rsqrtf((float)d0 + 1.0f);   // +1 = self-loop
    }
    if (2 * t + 1 < nn) {
        rowst[lo + 2 * t + 1] = rl[2 * t + 1];
        deg[lo + 2 * t + 1] = d1;
        dinv[lo + 2 * t + 1] = rsqrtf((float)d1 + 1.0f);
    }
    __syncthreads();
    for (unsigned i = rbase + t; i < rend; i += 256) {
        unsigned rec = grecs[i];
        unsigned l = rec & (QNODES - 1u);
        unsigned pos = rl[l] + atomicAdd(&cnt[l], 1u);
        srcs[pos] = (int)(rec >> QSHIFT);
    }
}

// ---------------------------------------------------------------------------
// GEMM1: hs[i][c] = (x[i] @ W1[:,c]) * dinv[i], padded to 16 ch (ch15 = 0).
// ---------------------------------------------------------------------------
__global__ __launch_bounds__(256) void gemm1_kernel(
    const float* __restrict__ x, const float* __restrict__ W1,
    const float* __restrict__ dinv, float* __restrict__ hs, int N) {
    __shared__ float Wl[N_IN * N_HIDP];
    for (int i = threadIdx.x; i < N_IN * N_HIDP; i += 256) {
        int k = i >> 4, c = i & 15;
        Wl[i] = (c < N_HID) ? W1[k * N_HID + c] : 0.f;
    }
    __syncthreads();
    const float4* __restrict__ Wl4 = (const float4*)Wl;
    const float4* __restrict__ x4  = (const float4*)x;

    int r0 = blockIdx.x * 512 + threadIdx.x;
    int r1 = r0 + 256;
    int r0c = r0 < N ? r0 : N - 1;
    int r1c = r1 < N ? r1 : N - 1;

    float acc0[16], acc1[16];
#pragma unroll
    for (int c = 0; c < 16; ++c) { acc0[c] = 0.f; acc1[c] = 0.f; }

    for (int k4 = 0; k4 < 32; ++k4) {
        float4 xv0 = x4[r0c * 32 + k4];
        float4 xv1 = x4[r1c * 32 + k4];
        float xs0[4] = {xv0.x, xv0.y, xv0.z, xv0.w};
        float xs1[4] = {xv1.x, xv1.y, xv1.z, xv1.w};
#pragma unroll
        for (int t = 0; t < 4; ++t) {
            int k = k4 * 4 + t;
            float4 wa = Wl4[k * 4 + 0];
            float4 wb = Wl4[k * 4 + 1];
            float4 wc = Wl4[k * 4 + 2];
            float4 wd = Wl4[k * 4 + 3];
            float wf[16] = {wa.x, wa.y, wa.z, wa.w, wb.x, wb.y, wb.z, wb.w,
                            wc.x, wc.y, wc.z, wc.w, wd.x, wd.y, wd.z, wd.w};
#pragma unroll
            for (int c = 0; c < 16; ++c) {
                acc0[c] = fmaf(xs0[t], wf[c], acc0[c]);
                acc1[c] = fmaf(xs1[t], wf[c], acc1[c]);
            }
        }
    }
    float4* __restrict__ hs4 = (float4*)hs;
    if (r0 < N) {
        float di = dinv[r0];
#pragma unroll
        for (int j = 0; j < 4; ++j)
            hs4[r0 * 4 + j] = make_float4(acc0[4*j]*di, acc0[4*j+1]*di,
                                          acc0[4*j+2]*di, acc0[4*j+3]*di);
    }
    if (r1 < N) {
        float di = dinv[r1];
#pragma unroll
        for (int j = 0; j < 4; ++j)
            hs4[r1 * 4 + j] = make_float4(acc1[4*j]*di, acc1[4*j+1]*di,
                                          acc1[4*j+2]*di, acc1[4*j+3]*di);
    }
}

// ---------------------------------------------------------------------------
// agg1: one 64-lane wave per dst node. Lanes = 4 edge-groups x 16 channels.
// 4 gathers in flight per lane (x4 unroll), shfl_xor reduce over groups.
// Epilogue fuses self-loop + bias + ReLU + dinv pre-scale for layer 2.
// No atomics: one coalesced 64 B store per node.
// ---------------------------------------------------------------------------
__global__ __launch_bounds__(256) void agg1_kernel(
    const int* __restrict__ srcs, const unsigned* __restrict__ rowst,
    const unsigned* __restrict__ deg, const float* __restrict__ hs,
    const float* __restrict__ dinv, const float* __restrict__ b1,
    float* __restrict__ hs2, int N) {
    int node = blockIdx.x * 4 + (threadIdx.x >> 6);
    if (node >= N) return;
    int lane = threadIdx.x & 63;
    int k = lane >> 4, c = lane & 15;
    unsigned dg = deg[node];
    unsigned base = rowst[node];
    float acc = 0.f;
    unsigned t = k;
    for (; t + 12 < dg; t += 16) {
        int s0 = srcs[base + t];
        int s1 = srcs[base + t + 4];
        int s2 = srcs[base + t + 8];
        int s3 = srcs[base + t + 12];
        float v0 = hs[(size_t)s0 * N_HIDP + c];
        float v1 = hs[(size_t)s1 * N_HIDP + c];
        float v2 = hs[(size_t)s2 * N_HIDP + c];
        float v3 = hs[(size_t)s3 * N_HIDP + c];
        acc += (v0 + v1) + (v2 + v3);
    }
    for (; t < dg; t += 4)
        acc += hs[(size_t)srcs[base + t] * N_HIDP + c];
    acc += __shfl_xor(acc, 16);
    acc += __shfl_xor(acc, 32);
    if (k == 0) {
        float di = dinv[node];
        float self = hs[(size_t)node * N_HIDP + c];
        float b = (c < N_HID) ? b1[c] : 0.f;
        float v = fmaxf(di * (acc + self) + b, 0.f);
        hs2[(size_t)node * N_HIDP + c] = v * di;
    }
}

// ---------------------------------------------------------------------------
// agg2: same gather-reduce, epilogue fuses the 15x32 W2 GEMM:
//   u[c] = dinv*(sum + hs2[i][c]);  out[i][j] = sum_k u[k]*W2[k][j] + b2[j]
// u is broadcast across the wave via __shfl; W2 staged in LDS.
// ---------------------------------------------------------------------------
__global__ __launch_bounds__(256) void agg2_kernel(
    const int* __restrict__ srcs, const unsigned* __restrict__ rowst,
    const unsigned* __restrict__ deg, const float* __restrict__ hs2,
    const float* __restrict__ dinv, const float* __restrict__ W2,
    const float* __restrict__ b2, float* __restrict__ out, int N) {
    __shared__ float W2l[N_HID * N_OUT];
    for (int t = threadIdx.x; t < N_HID * N_OUT; t += 256) W2l[t] = W2[t];
    __syncthreads();
    int node = blockIdx.x * 4 + (threadIdx.x >> 6);
    if (node >= N) return;
    int lane = threadIdx.x & 63;
    int k = lane >> 4, c = lane & 15;
    unsigned dg = deg[node];
    unsigned base = rowst[node];
    float acc = 0.f;
    unsigned t = k;
    for (; t + 12 < dg; t += 16) {
        int s0 = srcs[base + t];
        int s1 = srcs[base + t + 4];
        int s2 = srcs[base + t + 8];
        int s3 = srcs[base + t + 12];
        float v0 = hs2[(size_t)s0 * N_HIDP + c];
        float v1 = hs2[(size_t)s1 * N_HIDP + c];
        float v2 = hs2[(size_t)s2 * N_HIDP + c];
        float v3 = hs2[(size_t)s3 * N_HIDP + c];
        acc += (v0 + v1) + (v2 + v3);
    }
    for (; t < dg; t += 4)
        acc += hs2[(size_t)srcs[base + t] * N_HIDP + c];
    acc += __shfl_xor(acc, 16);
    acc += __shfl_xor(acc, 32);
    float di = dinv[node];
    float u = di * (acc + hs2[(size_t)node * N_HIDP + c]);  // c==15 -> 0
    int j = lane & 31;
    float a = b2[j];
#pragma unroll
    for (int kk = 0; kk < N_HID; ++kk)
        a = fmaf(__shfl(u, kk), W2l[kk * N_OUT + j], a);
    if (lane < 32) out[(size_t)node * N_OUT + j] = a;
}

// ---------------------------------------------------------------------------
extern "C" void kernel_launch(void* const* d_in, const int* in_sizes, int n_in,
                              void* d_out, int out_size, void* d_ws, size_t ws_size,
                              hipStream_t stream) {
    const float* x   = (const float*)d_in[0];
    const void*  eix = d_in[1];
    const float* W1  = (const float*)d_in[2];
    const float* b1  = (const float*)d_in[3];
    const float* W2  = (const float*)d_in[4];
    const float* b2  = (const float*)d_in[5];
    float* out = (float*)d_out;

    const int N = in_sizes[0] / N_IN;   // 200000
    const int E = in_sizes[1] / 2;      // 6400000
    const int NQ = (N + QNODES - 1) >> QSHIFT;   // 391 buckets

    char* ws = (char*)d_ws;
    size_t off = 0;
    auto alloc = [&](size_t bytes) -> void* {
        void* p = ws + off;
        off += (bytes + 255) & ~(size_t)255;
        return p;
    };
    unsigned* goff  = (unsigned*)alloc((size_t)NQ * NBLK1 * 4);  // hist -> scanned offsets
    unsigned* bsum  = (unsigned*)alloc((size_t)NQ * 4);
    unsigned* rowst = (unsigned*)alloc((size_t)N * 4);
    unsigned* deg   = (unsigned*)alloc((size_t)N * 4);
    float*    dinv  = (float*)alloc((size_t)N * 4);
    int*      srcs  = (int*)alloc((size_t)E * 4);
    float*    hs    = (float*)alloc((size_t)N * N_HIDP * 4);
    float*    hs2   = (float*)alloc((size_t)N * N_HIDP * 4);
    int*      flag  = (int*)alloc(256);
    // grecs (packed src<<9|local, E*4 = 25.6 MB) is dead once build_kernel
    // finishes, and hs/hs2 (2 x 12.8 MB, contiguous) are first written by
    // gemm1/agg1 which launch AFTER build on this stream -> alias them to
    // keep peak workspace ~55 MB.
    unsigned* grecs = (unsigned*)hs;

    detect_kernel<<<1, 256, 0, stream>>>((const int*)eix, flag);

    hist_kernel<<<NBLK1, 256, 0, stream>>>(eix, E, flag, goff, NQ);
    // scan M = NQ*NBLK1 elements; scanA block count == NQ (one per bucket row)
    scanA_kernel<<<NQ, 256, 0, stream>>>(goff, bsum);
    scanB_kernel<<<1, 256, 0, stream>>>(bsum, NQ);
    scanC_kernel<<<NQ, 256, 0, stream>>>(goff, bsum);
    place_kernel<<<NBLK1, 256, 0, stream>>>(eix, E, flag, goff, grecs, NQ);
    build_kernel<<<NQ, 256, 0, stream>>>(grecs, goff, E, N, NQ, rowst, deg, dinv, srcs);

    gemm1_kernel<<<(N + 511) / 512, 256, 0, stream>>>(x, W1, dinv, hs, N);
    agg1_kernel<<<(N + 3) / 4, 256, 0, stream>>>(srcs, rowst, deg, hs, dinv, b1, hs2, N);
    agg2_kernel<<<(N + 3) / 4, 256, 0, stream>>>(srcs, rowst, deg, hs2, dinv, W2, b2, out, N);
}